// Round 11
// baseline (585.873 us; speedup 1.0000x reference)
//
#include <hip/hip_runtime.h>
#include <math.h>

#define E_ 65536
#define N_ 16384
#define M_ 262144

typedef unsigned short u16;
typedef __attribute__((ext_vector_type(4))) float f32x4;
typedef __attribute__((ext_vector_type(8))) short bf16x8;
typedef __attribute__((ext_vector_type(4))) unsigned short u16x4;
typedef __attribute__((ext_vector_type(4))) float f4v;

__device__ __forceinline__ float b2f(u16 u) {
    union { unsigned u; float f; } x; x.u = ((unsigned)u) << 16; return x.f;
}
__device__ __forceinline__ u16 f2b(float f) {
    union { float f; unsigned u; } x; x.f = f;
    unsigned r = x.u + 0x7FFFu + ((x.u >> 16) & 1u);
    return (u16)(r >> 16);
}
// tanh-form GELU via rcp (no -ffast-math: '/' is ~10 instr, rcp+mul is 2; ~1ulp, bf16-safe)
__device__ __forceinline__ float gelu_f(float x) {
    float y = 1.5957691216057308f * x * (1.0f + 0.044715f * x * x);
    return x * __builtin_amdgcn_rcpf(1.0f + __expf(-y));
}

#define GLDS(gp, lp) __builtin_amdgcn_global_load_lds( \
    (const __attribute__((address_space(1))) void*)(gp), \
    (__attribute__((address_space(3))) void*)(lp), 16, 0, 0)

// ---------------- zero int buffer ----------------
__global__ void ge_zero(int* __restrict__ p, int n) {
    int i = blockIdx.x * 256 + threadIdx.x;
    if (i < n) p[i] = 0;
}

// ---------------- weight convert/transpose/pack ----------------
__global__ void ge_convw(const float* __restrict__ Wq, const float* __restrict__ Wk,
                         const float* __restrict__ Wv, const float* __restrict__ bq,
                         const float* __restrict__ bk, const float* __restrict__ bv,
                         const float* __restrict__ Wo, const float* __restrict__ W1,
                         const float* __restrict__ W2, const float* __restrict__ We2n,
                         u16* __restrict__ WqkvT, float* __restrict__ bqkv,
                         u16* __restrict__ WoT, u16* __restrict__ W1T,
                         u16* __restrict__ W2T, u16* __restrict__ We2nT) {
    long i = (long)blockIdx.x * 256 + threadIdx.x;
    if (i < 196608) {  // WqkvT [768][256]
        int n = (int)(i >> 8), k = (int)(i & 255);
        const float* W = (n < 256) ? Wq : ((n < 512) ? Wk : Wv);
        int nn = n & 255;
        WqkvT[i] = f2b(W[k * 256 + nn]);
        return;
    }
    i -= 196608;
    if (i < 768) { bqkv[i] = (i < 256) ? bq[i] : ((i < 512) ? bk[i - 256] : bv[i - 512]); return; }
    i -= 768;
    if (i < 65536) { int n = (int)(i >> 8), k = (int)(i & 255); WoT[i] = f2b(Wo[k * 256 + n]); return; }
    i -= 65536;
    if (i < 262144) { int n = (int)(i >> 8), k = (int)(i & 255); W1T[i] = f2b(W1[k * 1024 + n]); return; }
    i -= 262144;
    if (i < 262144) { int n = (int)(i / 1024), k = (int)(i % 1024); W2T[i] = f2b(W2[k * 256 + n]); return; }
    i -= 262144;
    if (i < 65536) { int n = (int)(i >> 8), k = (int)(i & 255); We2nT[i] = f2b(We2n[k * 256 + n]); return; }
}

// ---------------- LayerNorm row (D=256), f32 in -> bf16 out ----------------
__global__ __launch_bounds__(256) void ge_ln(const float* __restrict__ in,
                                             const float* __restrict__ s,
                                             const float* __restrict__ b,
                                             u16* __restrict__ out) {
    int tid = threadIdx.x, l = tid & 63, w = tid >> 6;
    long r = (long)blockIdx.x * 4 + w;
    f4v x = *(const f4v*)&in[r * 256 + 4 * l];
    float sum = x[0] + x[1] + x[2] + x[3];
#pragma unroll
    for (int off = 1; off < 64; off <<= 1) sum += __shfl_xor(sum, off);
    float mean = sum * (1.0f / 256.0f);
    float d0 = x[0] - mean, d1 = x[1] - mean, d2 = x[2] - mean, d3 = x[3] - mean;
    float ss = d0 * d0 + d1 * d1 + d2 * d2 + d3 * d3;
#pragma unroll
    for (int off = 1; off < 64; off <<= 1) ss += __shfl_xor(ss, off);
    float rs = rsqrtf(ss * (1.0f / 256.0f) + 1e-5f);
    u16x4 o;
    o[0] = f2b(d0 * rs * s[4 * l + 0] + b[4 * l + 0]);
    o[1] = f2b(d1 * rs * s[4 * l + 1] + b[4 * l + 1]);
    o[2] = f2b(d2 * rs * s[4 * l + 2] + b[4 * l + 2]);
    o[3] = f2b(d3 * rs * s[4 * l + 3] + b[4 * l + 3]);
    *(u16x4*)&out[r * 256 + 4 * l] = o;
}

// ---------------- CSR build: count, hierarchical scan, fill ----------------
__global__ void ge_count(const int* __restrict__ idx, int* __restrict__ cnt, int n) {
    int i = blockIdx.x * 256 + threadIdx.x;
    if (i < n) atomicAdd(&cnt[idx[i]], 1);
}

__global__ __launch_bounds__(256) void ge_bsum(const int* __restrict__ cnt,
                                               int* __restrict__ bsum, int n) {
    int i = blockIdx.x * 256 + threadIdx.x;
    int v = (i < n) ? cnt[i] : 0;
#pragma unroll
    for (int off = 1; off < 64; off <<= 1) v += __shfl_xor(v, off);
    __shared__ int ws_[4];
    int l = threadIdx.x & 63, w = threadIdx.x >> 6;
    if (l == 0) ws_[w] = v;
    __syncthreads();
    if (threadIdx.x == 0) bsum[blockIdx.x] = ws_[0] + ws_[1] + ws_[2] + ws_[3];
}

__global__ __launch_bounds__(256) void ge_bscan(int* __restrict__ bsum, int nb) {
    __shared__ int lds[256];
    int tid = threadIdx.x;
    int v = (tid < nb) ? bsum[tid] : 0;
    lds[tid] = v;
    __syncthreads();
#pragma unroll
    for (int off = 1; off < 256; off <<= 1) {
        int t = (tid >= off) ? lds[tid - off] : 0;
        __syncthreads();
        lds[tid] += t;
        __syncthreads();
    }
    if (tid < nb) bsum[tid] = lds[tid] - v;  // exclusive
}

__global__ __launch_bounds__(256) void ge_cscan(const int* __restrict__ cnt,
                                                const int* __restrict__ bsum,
                                                int* __restrict__ rowStart,
                                                int* __restrict__ cursor,
                                                float* __restrict__ ldeg, int n) {
    __shared__ int lds[256];
    int tid = threadIdx.x;
    int i = blockIdx.x * 256 + tid;
    int c = (i < n) ? cnt[i] : 0;
    lds[tid] = c;
    __syncthreads();
#pragma unroll
    for (int off = 1; off < 256; off <<= 1) {
        int t = (tid >= off) ? lds[tid - off] : 0;
        __syncthreads();
        lds[tid] += t;
        __syncthreads();
    }
    if (i < n) {
        int ex = bsum[blockIdx.x] + lds[tid] - c;
        rowStart[i] = ex;
        cursor[i] = ex;
        if (ldeg) ldeg[i] = log1pf((float)c);
        if (i == n - 1) rowStart[n] = ex + c;
    }
}

__global__ void ge_fill(const int* __restrict__ idx, int* __restrict__ cursor,
                        int* __restrict__ csr, int n, int modE) {
    int i = blockIdx.x * 256 + threadIdx.x;
    if (i < n) {
        int slot = atomicAdd(&cursor[idx[i]], 1);
        csr[slot] = (modE && i >= modE) ? (i - modE) : i;
    }
}

__global__ void ge_fill_attn(const int* __restrict__ dst, const int* __restrict__ src,
                             const float* __restrict__ eeb, int* __restrict__ cursor,
                             int* __restrict__ csrSrc, float* __restrict__ biasCsr, int n) {
    int i = blockIdx.x * 256 + threadIdx.x;
    if (i < n) {
        int slot = atomicAdd(&cursor[dst[i]], 1);
        csrSrc[slot] = src[i];
        f4v b0 = *(const f4v*)&eeb[(size_t)i * 8];
        f4v b1 = *(const f4v*)&eeb[(size_t)i * 8 + 4];
        *(f4v*)&biasCsr[(size_t)slot * 8] = b0;
        *(f4v*)&biasCsr[(size_t)slot * 8 + 4] = b1;
    }
}

// ---------------- GEMM: 128x128 tile, grouped block order (R10-proven) ----------------
// EPI 1: out f32  = C + bias + res               (Wo + residual -> h1)
// EPI 4: out f32  = C + bias + res               (We2n + x)
// EPI 5: QKV: q -> outB[E][256]; k,v interleaved 8-wide -> outB2[E][512]
template <int EPI>
__global__ __launch_bounds__(256) void ge_gemm(
    const u16* __restrict__ A, const u16* __restrict__ Bt, int K, int nxt,
    const float* __restrict__ bias, const float* __restrict__ res,
    const float* __restrict__ ldeg, const float* __restrict__ dcoef,
    float* __restrict__ outF, u16* __restrict__ outB, u16* __restrict__ outB2,
    int ldOut) {
    __shared__ __align__(16) char smem[32768];
    const int tid = threadIdx.x;
    const int l = tid & 63, w = tid >> 6;
    // grouped block-order remap (bijective; nxt % 64 == 0 for all our grids)
    const int ny = gridDim.x / nxt;
    const int gsz = 64 * ny;
    const int bid = blockIdx.x;
    const int xt = (bid / gsz) * 64 + (bid % gsz) % 64;
    const int yt = (bid % gsz) / 64;
    const int rowBase = xt * 128, colBase = yt * 128;
    const int ar = tid >> 2, aq = tid & 3;
    const int aqs = aq ^ (ar & 3);  // source-side chunk swizzle (R4/R8-proven)
    const u16* Ag = A + (size_t)(rowBase + ar) * K + aqs * 8;
    const u16* Bg = Bt + (size_t)(colBase + ar) * K + aqs * 8;
    const size_t row64 = (size_t)64 * K;

    f32x4 acc[4][4] = {};
    const int lr = l & 15;
    const int ks2 = (((l >> 4) ^ (l & 3)) << 3);  // read-side swizzled chunk (R4/R8-proven)
    const int wr = (w >> 1) * 64, wc = (w & 1) * 64;
    const int nt = K >> 5;

    auto STAGE = [&](int b, int t) {
        const int kk = t * 32;
        char* dA = smem + b * 8192 + w * 1024;
        char* dB = smem + 16384 + b * 8192 + w * 1024;
        GLDS(Ag + kk, dA);
        GLDS(Ag + kk + row64, dA + 4096);
        GLDS(Bg + kk, dB);
        GLDS(Bg + kk + row64, dB + 4096);
    };

    STAGE(0, 0);
    __syncthreads();
    int cur = 0;
    for (int t = 0; t < nt; ++t) {
        if (t + 1 < nt) STAGE(cur ^ 1, t + 1);
        const u16* bufA = (const u16*)(smem + cur * 8192);
        const u16* bufB = (const u16*)(smem + 16384 + cur * 8192);
        bf16x8 af[4], bfr[4];
#pragma unroll
        for (int mi = 0; mi < 4; mi++) af[mi] = *(const bf16x8*)&bufA[(wr + mi * 16 + lr) * 32 + ks2];
#pragma unroll
        for (int ni = 0; ni < 4; ni++) bfr[ni] = *(const bf16x8*)&bufB[(wc + ni * 16 + lr) * 32 + ks2];
#pragma unroll
        for (int mi = 0; mi < 4; mi++)
#pragma unroll
            for (int ni = 0; ni < 4; ni++)
                acc[mi][ni] = __builtin_amdgcn_mfma_f32_16x16x32_bf16(af[mi], bfr[ni], acc[mi][ni], 0, 0, 0);
        if (t + 1 < nt) {
            __syncthreads();
            cur ^= 1;
        }
    }

    const int r0 = (l >> 4) * 4;
    if constexpr (EPI == 5) {
        // bf16 outputs: transpose through LDS with row-group XOR swizzle
        __syncthreads();
        u16* ep = (u16*)smem;  // [128][128]
#pragma unroll
        for (int mi = 0; mi < 4; mi++) {
#pragma unroll
            for (int ni = 0; ni < 4; ni++) {
#pragma unroll
                for (int r = 0; r < 4; r++) {
                    int rl = wr + mi * 16 + r0 + r;
                    int cl = wc + ni * 16 + lr;
                    float c = acc[mi][ni][r] + bias[colBase + cl];
                    ep[rl * 128 + (cl ^ (((rl >> 2) & 3) << 4))] = f2b(c);
                }
            }
        }
        __syncthreads();
#pragma unroll
        for (int j = 0; j < 8; j++) {
            int lin = tid + j * 256;
            int row = lin >> 4, ch = lin & 15;
            int grow = rowBase + row;
            bf16x8 v = *(const bf16x8*)&ep[row * 128 + ((ch * 8) ^ (((row >> 2) & 3) << 4))];
            int gcol0 = colBase + ch * 8;
            u16x4 vlo = *((const u16x4*)&v);
            u16x4 vhi = *(((const u16x4*)&v) + 1);
            if (gcol0 < 256) {
                *(bf16x8*)&outB[(size_t)grow * 256 + gcol0] = v;
            } else if (gcol0 < 512) {
                int d0 = (gcol0 - 256) >> 2;  // even
                *(u16x4*)&outB2[(size_t)grow * 512 + 8 * d0] = vlo;
                *(u16x4*)&outB2[(size_t)grow * 512 + 8 * (d0 + 1)] = vhi;
            } else {
                int d0 = (gcol0 - 512) >> 2;  // even
                *(u16x4*)&outB2[(size_t)grow * 512 + 8 * d0 + 4] = vlo;
                *(u16x4*)&outB2[(size_t)grow * 512 + 8 * (d0 + 1) + 4] = vhi;
            }
        }
    } else {
#pragma unroll
        for (int mi = 0; mi < 4; mi++) {
#pragma unroll
            for (int ni = 0; ni < 4; ni++) {
#pragma unroll
                for (int r = 0; r < 4; r++) {
                    int grow = rowBase + wr + mi * 16 + r0 + r;
                    int gcol = colBase + wc + ni * 16 + lr;
                    float c = acc[mi][ni][r];
                    size_t oidx = (size_t)grow * ldOut + gcol;
                    outF[oidx] = c + bias[gcol] + res[(size_t)grow * 256 + gcol];
                }
            }
        }
    }
}

// ---------------- fused FFN (staged weights): out = (gelu(h1n@W1+b1)@W2 + b2 + h1)*degscale
// 64-row blocks. LDS 64KB: Abuf[64][256] (32KB, XOR-chunk swizzle) | Hbuf[64][128] (16KB,
// XOR swizzle) | B1 dbuf 2x8KB (W1T chunk K-slices, GLDS-staged, double-buffered).
// Phase A (per 128-hidden chunk): hchunk = gelu(A @ W1T_chunk^T + b1) -> Hbuf.
// Phase B: acc2 += hchunk @ W2T_chunk^T (W2T from global; 512KB, L2-resident).
__global__ __launch_bounds__(256) void ge_ffn(
    const u16* __restrict__ h1n, const u16* __restrict__ W1T, const float* __restrict__ b1,
    const u16* __restrict__ W2T, const float* __restrict__ b2,
    const float* __restrict__ h1, const float* __restrict__ ldeg,
    const float* __restrict__ dcoef, float* __restrict__ outE) {
    __shared__ __align__(16) char smem[65536];
    u16* Abuf = (u16*)smem;            // [64][256], chunk16 slot s of row r holds global chunk s^(r&7)
    u16* Hbuf = (u16*)(smem + 32768);  // [64][128], slot s of row r holds cols (col>>3)=s^(r&7)
    const int tid = threadIdx.x;
    const int l = tid & 63, w = tid >> 6;
    const int r0 = blockIdx.x * 64;
    const int lr = l & 15, q = l >> 4;
    const int wr = (w >> 1) * 32, wc = (w & 1) * 64;     // phase A quadrant (32x64 of 64x128)
    const int wr2 = (w >> 1) * 32, wc2 = (w & 1) * 128;  // phase B quadrant (32x128 of 64x256)

    // ---- stage A: h1n rows r0..r0+63, pre-swizzled global source ----
#pragma unroll
    for (int j = 0; j < 8; j++) {
        int off = j * 4096 + w * 1024 + l * 16;
        int row = off >> 9;
        int c32 = (off & 511) >> 4;
        const u16* src = h1n + (size_t)(r0 + row) * 256 + (size_t)((c32 ^ (row & 7)) * 8);
        GLDS(src, smem + j * 4096 + w * 1024);
    }

    auto stageB1 = [&](int half, int c, int ks) {
#pragma unroll
        for (int j = 0; j < 2; j++) {
            int off = j * 4096 + w * 1024 + l * 16;
            int row = off >> 6;
            int slot = (off & 63) >> 4;
            const u16* src = W1T + (size_t)(c * 128 + row) * 256 + ks * 32
                             + (size_t)((slot ^ ((row >> 1) & 3)) * 8);
            GLDS(src, smem + 49152 + half * 8192 + j * 4096 + w * 1024);
        }
    };
    stageB1(0, 0, 0);

    f32x4 acc2[2][8] = {};

    for (int c = 0; c < 8; ++c) {
        __syncthreads();  // staged data visible (A + B1[0] for c=0; B1[0] prefetch for c>0)
        // ---- phase A: hchunk = gelu(A @ W1T_chunk + b1) ----
        f32x4 accA[2][4] = {};
#pragma unroll 1
        for (int ks = 0; ks < 8; ++ks) {
            if (ks < 7) stageB1((ks + 1) & 1, c, ks + 1);
            const u16* Bh = (const u16*)(smem + 49152 + (ks & 1) * 8192);
            bf16x8 af[2], bf[4];
#pragma unroll
            for (int mi = 0; mi < 2; mi++) {
                int row = wr + mi * 16 + lr;
                af[mi] = *(const bf16x8*)&Abuf[row * 256 + (((ks * 4 + q) ^ (row & 7)) * 8)];
            }
#pragma unroll
            for (int ni = 0; ni < 4; ni++) {
                int hc = wc + ni * 16 + lr;
                bf[ni] = *(const bf16x8*)&Bh[hc * 32 + ((q ^ ((hc >> 1) & 3)) * 8)];
            }
#pragma unroll
            for (int mi = 0; mi < 2; mi++)
#pragma unroll
                for (int ni = 0; ni < 4; ni++)
                    accA[mi][ni] = __builtin_amdgcn_mfma_f32_16x16x32_bf16(af[mi], bf[ni], accA[mi][ni], 0, 0, 0);
            __syncthreads();
        }
        // ---- gelu -> Hbuf (swizzled) ----
#pragma unroll
        for (int mi = 0; mi < 2; mi++) {
#pragma unroll
            for (int ni = 0; ni < 4; ni++) {
#pragma unroll
                for (int rr = 0; rr < 4; rr++) {
                    int row = wr + mi * 16 + q * 4 + rr;
                    int col = wc + ni * 16 + lr;
                    float v = accA[mi][ni][rr] + b1[c * 128 + col];
                    v = gelu_f(v);
                    int slot = (col >> 3) ^ (row & 7);
                    Hbuf[row * 128 + slot * 8 + (col & 7)] = f2b(v);
                }
            }
        }
        if (c < 7) stageB1(0, c + 1, 0);  // prefetch next chunk's first B1 slice
        __syncthreads();                   // Hbuf visible (+ drains prefetch)
        // ---- phase B: acc2 += hchunk @ W2T_chunk ----
#pragma unroll 1
        for (int ks2 = 0; ks2 < 4; ++ks2) {
            bf16x8 hf[2], wf[8];
#pragma unroll
            for (int ni = 0; ni < 8; ni++) {
                int wrow = wc2 + ni * 16 + lr;
                wf[ni] = *(const bf16x8*)&W2T[(size_t)wrow * 1024 + c * 128 + ks2 * 32 + q * 8];
            }
#pragma unroll
            for (int mi = 0; mi < 2; mi++) {
                int row = wr2 + mi * 16 + lr;
                hf[mi] = *(const bf16x8*)&Hbuf[row * 128 + (((ks2 * 4 + q) ^ (row & 7)) * 8)];
            }
#pragma unroll
            for (int mi = 0; mi < 2; mi++)
#pragma unroll
                for (int ni = 0; ni < 8; ni++)
                    acc2[mi][ni] = __builtin_amdgcn_mfma_f32_16x16x32_bf16(hf[mi], wf[ni], acc2[mi][ni], 0, 0, 0);
        }
    }

    // ---- epilogue: + b2 + h1 residual, degree scale -> f32 out ----
#pragma unroll
    for (int mi = 0; mi < 2; mi++) {
#pragma unroll
        for (int ni = 0; ni < 8; ni++) {
#pragma unroll
            for (int rr = 0; rr < 4; rr++) {
                int grow = r0 + wr2 + mi * 16 + q * 4 + rr;
                int gcol = wc2 + ni * 16 + lr;
                float v = acc2[mi][ni][rr] + b2[gcol] + h1[(size_t)grow * 256 + gcol];
                outE[(size_t)grow * 256 + gcol] =
                    v * (dcoef[2 * gcol] + ldeg[grow] * dcoef[2 * gcol + 1]);
            }
        }
    }
}

// ---------------- per-dst-segment attention: single-pass softmax + V agg ----------------
__global__ __launch_bounds__(256) void ge_attn(const u16* __restrict__ qb,
                                               const u16* __restrict__ kvb,
                                               const float* __restrict__ biasCsr,
                                               const int* __restrict__ csrSrc,
                                               const int* __restrict__ rowStart,
                                               u16* __restrict__ agg) {
    int tid = threadIdx.x, l = tid & 63, w = tid >> 6;
    int e = blockIdx.x * 4 + w;
    int g = l >> 3;
    const float scale = 0.17677669529663687f;  // 32^-0.5
    u16x4 qv = *(const u16x4*)&qb[(size_t)e * 256 + 4 * l];
    float q0 = b2f(qv[0]), q1 = b2f(qv[1]), q2 = b2f(qv[2]), q3 = b2f(qv[3]);
    int s0 = rowStart[e], s1 = rowStart[e + 1];

    float sum = 0.0f, a0 = 0.0f, a1 = 0.0f, a2 = 0.0f, a3 = 0.0f;
    if (s0 < s1) {
        int sc = csrSrc[s0];
        bf16x8 kvc = *(const bf16x8*)&kvb[(size_t)sc * 512 + 8 * l];
        float bc = biasCsr[(size_t)s0 * 8 + g];
        for (int i = s0; i < s1; i++) {
            int inx = (i + 1 < s1) ? (i + 1) : i;
            int sn = csrSrc[inx];
            bf16x8 kvn = *(const bf16x8*)&kvb[(size_t)sn * 512 + 8 * l];
            float bn = biasCsr[(size_t)inx * 8 + g];
            float p = q0 * b2f((u16)kvc[0]) + q1 * b2f((u16)kvc[1]) +
                      q2 * b2f((u16)kvc[2]) + q3 * b2f((u16)kvc[3]);
            p += __shfl_xor(p, 1);
            p += __shfl_xor(p, 2);
            p += __shfl_xor(p, 4);
            float ex = __expf(p * scale + bc);  // logits bounded, no max pass needed
            sum += ex;
            a0 += ex * b2f((u16)kvc[4]);
            a1 += ex * b2f((u16)kvc[5]);
            a2 += ex * b2f((u16)kvc[6]);
            a3 += ex * b2f((u16)kvc[7]);
            kvc = kvn;
            bc = bn;
        }
    }
    float inv = 1.0f / (sum + 1e-16f);
    u16x4 o;
    o[0] = f2b(a0 * inv);
    o[1] = f2b(a1 * inv);
    o[2] = f2b(a2 * inv);
    o[3] = f2b(a3 * inv);
    *(u16x4*)&agg[(size_t)e * 256 + 4 * l] = o;
}

// ---------------- node aggregation: sum edge_out rows per node -> bf16 ----------------
__global__ __launch_bounds__(256) void ge_nodeagg(const float* __restrict__ edge_out,
                                                  const int* __restrict__ rowStart,
                                                  const int* __restrict__ csr,
                                                  u16* __restrict__ nmsg) {
    int tid = threadIdx.x, l = tid & 63, w = tid >> 6;
    int n = blockIdx.x * 4 + w;
    int s0 = rowStart[n], s1 = rowStart[n + 1];
    float a0 = 0.0f, a1 = 0.0f, a2 = 0.0f, a3 = 0.0f;
    for (int i = s0; i < s1; i++) {
        int e = csr[i];
        f4v v = *(const f4v*)&edge_out[(size_t)e * 256 + 4 * l];
        a0 += v[0]; a1 += v[1]; a2 += v[2]; a3 += v[3];
    }
    u16x4 o;
    o[0] = f2b(a0); o[1] = f2b(a1); o[2] = f2b(a2); o[3] = f2b(a3);
    *(u16x4*)&nmsg[(size_t)n * 256 + 4 * l] = o;
}

extern "C" void kernel_launch(void* const* d_in, const int* in_sizes, int n_in,
                              void* d_out, int out_size, void* d_ws, size_t ws_size,
                              hipStream_t stream) {
    (void)in_sizes; (void)n_in; (void)out_size; (void)ws_size;
    const float* edge_attr = (const float*)d_in[0];
    const float* x = (const float*)d_in[1];
    const int* src_e = (const int*)d_in[2];
    const int* dst_e = (const int*)d_in[3];
    const int* edge_index = (const int*)d_in[4];
    const float* eeb = (const float*)d_in[5];
    const float* ln1_s = (const float*)d_in[6];
    const float* ln1_b = (const float*)d_in[7];
    const float* Wq = (const float*)d_in[8];
    const float* bq = (const float*)d_in[9];
    const float* Wk = (const float*)d_in[10];
    const float* bk = (const float*)d_in[11];
    const float* Wv = (const float*)d_in[12];
    const float* bv = (const float*)d_in[13];
    const float* Wo = (const float*)d_in[14];
    const float* bo = (const float*)d_in[15];
    const float* ln2_s = (const float*)d_in[16];
    const float* ln2_b = (const float*)d_in[17];
    const float* W1 = (const float*)d_in[18];
    const float* b1 = (const float*)d_in[19];
    const float* W2 = (const float*)d_in[20];
    const float* b2 = (const float*)d_in[21];
    const float* deg_coef = (const float*)d_in[22];
    const float* We2n = (const float*)d_in[23];
    const float* be2n = (const float*)d_in[24];

    char* ws = (char*)d_ws;
    size_t off = 0;
    auto alloc = [&](size_t bytes) { char* p = ws + off; off += (bytes + 255) & ~(size_t)255; return p; };
    u16* qb = (u16*)alloc((size_t)E_ * 256 * 2);
    u16* kvb = (u16*)alloc((size_t)E_ * 512 * 2);
    u16* agg = (u16*)alloc((size_t)E_ * 256 * 2);
    float* h1 = (float*)alloc((size_t)E_ * 256 * 4);
    u16* en = (u16*)alloc((size_t)E_ * 256 * 2);
    u16* h1n = en;  // reuse after QKV GEMM
    u16* nmsg = (u16*)alloc((size_t)N_ * 256 * 2);
    u16* WqkvT = (u16*)alloc(768 * 256 * 2);
    float* bqkv = (float*)alloc(768 * 4);
    u16* WoT = (u16*)alloc(256 * 256 * 2);
    u16* W1T = (u16*)alloc(1024 * 256 * 2);
    u16* W2T = (u16*)alloc(256 * 1024 * 2);
    u16* We2nT = (u16*)alloc(256 * 256 * 2);
    int* cntE = (int*)alloc((size_t)E_ * 4);
    int* cntN = (int*)alloc((size_t)N_ * 4);
    int* rowStartE = (int*)alloc((size_t)(E_ + 1) * 4);
    int* cursorE = (int*)alloc((size_t)E_ * 4);
    int* csrSrc = (int*)alloc((size_t)M_ * 4);
    float* biasCsr = (float*)alloc((size_t)M_ * 8 * 4);
    float* ldeg = (float*)alloc((size_t)E_ * 4);
    int* rowStartN = (int*)alloc((size_t)(N_ + 1) * 4);
    int* cursorN = (int*)alloc((size_t)N_ * 4);
    int* csrN = (int*)alloc((size_t)2 * E_ * 4);
    int* bsumE = (int*)alloc(256 * 4);
    int* bsumN = (int*)alloc(64 * 4);

    float* out_edge = (float*)d_out;
    float* out_node = out_edge + (size_t)E_ * 256;

    // CSR + weights prep
    ge_zero<<<(E_ + N_) / 256, 256, 0, stream>>>(cntE, E_ + N_);
    ge_convw<<<3331, 256, 0, stream>>>(Wq, Wk, Wv, bq, bk, bv, Wo, W1, W2, We2n,
                                       WqkvT, bqkv, WoT, W1T, W2T, We2nT);
    ge_ln<<<E_ / 4, 256, 0, stream>>>(edge_attr, ln1_s, ln1_b, en);
    ge_count<<<M_ / 256, 256, 0, stream>>>(dst_e, cntE, M_);
    ge_count<<<2 * E_ / 256, 256, 0, stream>>>(edge_index, cntN, 2 * E_);
    ge_bsum<<<E_ / 256, 256, 0, stream>>>(cntE, bsumE, E_);
    ge_bscan<<<1, 256, 0, stream>>>(bsumE, E_ / 256);
    ge_cscan<<<E_ / 256, 256, 0, stream>>>(cntE, bsumE, rowStartE, cursorE, ldeg, E_);
    ge_bsum<<<N_ / 256, 256, 0, stream>>>(cntN, bsumN, N_);
    ge_bscan<<<1, 256, 0, stream>>>(bsumN, N_ / 256);
    ge_cscan<<<N_ / 256, 256, 0, stream>>>(cntN, bsumN, rowStartN, cursorN, nullptr, N_);
    ge_fill_attn<<<M_ / 256, 256, 0, stream>>>(dst_e, src_e, eeb, cursorE, csrSrc, biasCsr, M_);
    ge_fill<<<2 * E_ / 256, 256, 0, stream>>>(edge_index, cursorN, csrN, 2 * E_, E_);

    // QKV projection: en @ WqkvT -> qb (E,256) + kvb (E,512 interleaved)
    ge_gemm<5><<<(E_ / 128) * 6, 256, 0, stream>>>(en, WqkvT, 256, E_ / 128, bqkv,
                                                   nullptr, nullptr, nullptr, nullptr, qb, kvb, 768);
    // segment attention -> agg bf16 (E,256)
    ge_attn<<<E_ / 4, 256, 0, stream>>>(qb, kvb, biasCsr, csrSrc, rowStartE, agg);
    // Wo + residual -> h1 f32
    ge_gemm<1><<<(E_ / 128) * 2, 256, 0, stream>>>(agg, WoT, 256, E_ / 128, bo,
                                                   edge_attr, nullptr, nullptr, h1, nullptr, nullptr, 256);
    // LN2 -> h1n bf16
    ge_ln<<<E_ / 4, 256, 0, stream>>>(h1, ln2_s, ln2_b, h1n);
    // fused FFN (staged weights) -> edge_out f32 (d_out)
    ge_ffn<<<E_ / 64, 256, 0, stream>>>(h1n, W1T, b1, W2T, b2, h1, ldeg, deg_coef, out_edge);
    // node aggregation -> nmsg bf16 (N,256)
    ge_nodeagg<<<N_ / 4, 256, 0, stream>>>(out_edge, rowStartN, csrN, nmsg);
    // e2n projection + x residual -> node_out f32 (d_out tail)
    ge_gemm<4><<<(N_ / 128) * 2, 256, 0, stream>>>(nmsg, We2nT, 256, N_ / 128, be2n,
                                                   x, nullptr, nullptr, out_node, nullptr, nullptr, 256);
}

// Round 12
// 427.270 us; speedup vs baseline: 1.3712x; 1.3712x over previous
//
#include <hip/hip_runtime.h>
#include <math.h>

#define E_ 65536
#define N_ 16384
#define M_ 262144

typedef unsigned short u16;
typedef __attribute__((ext_vector_type(4))) float f32x4;
typedef __attribute__((ext_vector_type(8))) short bf16x8;
typedef __attribute__((ext_vector_type(4))) unsigned short u16x4;
typedef __attribute__((ext_vector_type(2))) unsigned int u32x2;
typedef __attribute__((ext_vector_type(4))) float f4v;

__device__ __forceinline__ float b2f(u16 u) {
    union { unsigned u; float f; } x; x.u = ((unsigned)u) << 16; return x.f;
}
__device__ __forceinline__ u16 f2b(float f) {
    union { float f; unsigned u; } x; x.f = f;
    unsigned r = x.u + 0x7FFFu + ((x.u >> 16) & 1u);
    return (u16)(r >> 16);
}
// tanh-form GELU via rcp (validated R7/R11; ~1ulp, bf16-safe)
__device__ __forceinline__ float gelu_f(float x) {
    float y = 1.5957691216057308f * x * (1.0f + 0.044715f * x * x);
    return x * __builtin_amdgcn_rcpf(1.0f + __expf(-y));
}

#define GLDS(gp, lp) __builtin_amdgcn_global_load_lds( \
    (const __attribute__((address_space(1))) void*)(gp), \
    (__attribute__((address_space(3))) void*)(lp), 16, 0, 0)

// ---------------- zero int buffer ----------------
__global__ void ge_zero(int* __restrict__ p, int n) {
    int i = blockIdx.x * 256 + threadIdx.x;
    if (i < n) p[i] = 0;
}

// ---------------- weight convert/transpose/pack ----------------
// W2T K-dim is QUAD-PERMUTED to match EPI2's direct-store ffh layout:
// stored k = base64 + lr*4 + ni  <->  true hidden = base64 + ni*16 + lr.
__global__ void ge_convw(const float* __restrict__ Wq, const float* __restrict__ Wk,
                         const float* __restrict__ Wv, const float* __restrict__ bq,
                         const float* __restrict__ bk, const float* __restrict__ bv,
                         const float* __restrict__ Wo, const float* __restrict__ W1,
                         const float* __restrict__ W2, const float* __restrict__ We2n,
                         u16* __restrict__ WqkvT, float* __restrict__ bqkv,
                         u16* __restrict__ WoT, u16* __restrict__ W1T,
                         u16* __restrict__ W2T, u16* __restrict__ We2nT) {
    long i = (long)blockIdx.x * 256 + threadIdx.x;
    if (i < 196608) {  // WqkvT [768][256]
        int n = (int)(i >> 8), k = (int)(i & 255);
        const float* W = (n < 256) ? Wq : ((n < 512) ? Wk : Wv);
        int nn = n & 255;
        WqkvT[i] = f2b(W[k * 256 + nn]);
        return;
    }
    i -= 196608;
    if (i < 768) { bqkv[i] = (i < 256) ? bq[i] : ((i < 512) ? bk[i - 256] : bv[i - 512]); return; }
    i -= 768;
    if (i < 65536) { int n = (int)(i >> 8), k = (int)(i & 255); WoT[i] = f2b(Wo[k * 256 + n]); return; }
    i -= 65536;
    if (i < 262144) { int n = (int)(i >> 8), k = (int)(i & 255); W1T[i] = f2b(W1[k * 1024 + n]); return; }
    i -= 262144;
    if (i < 262144) {  // W2T [256][1024], quad-permuted K
        int n = (int)(i / 1024), k = (int)(i % 1024);
        int k64 = k & 63, base = k - k64;
        int old_k = base + (k64 & 3) * 16 + (k64 >> 2);
        W2T[i] = f2b(W2[old_k * 256 + n]);
        return;
    }
    i -= 262144;
    if (i < 65536) { int n = (int)(i >> 8), k = (int)(i & 255); We2nT[i] = f2b(We2n[k * 256 + n]); return; }
}

// ---------------- LayerNorm row (D=256) -> bf16 out; IN: 0=f32, 1=bf16 ----------------
template <int BF16IN>
__global__ __launch_bounds__(256) void ge_ln(const void* __restrict__ in,
                                             const float* __restrict__ s,
                                             const float* __restrict__ b,
                                             u16* __restrict__ out) {
    int tid = threadIdx.x, l = tid & 63, w = tid >> 6;
    long r = (long)blockIdx.x * 4 + w;
    float x0, x1, x2, x3;
    if constexpr (BF16IN) {
        u16x4 xv = *(const u16x4*)&((const u16*)in)[r * 256 + 4 * l];
        x0 = b2f(xv[0]); x1 = b2f(xv[1]); x2 = b2f(xv[2]); x3 = b2f(xv[3]);
    } else {
        f4v x = *(const f4v*)&((const float*)in)[r * 256 + 4 * l];
        x0 = x[0]; x1 = x[1]; x2 = x[2]; x3 = x[3];
    }
    float sum = x0 + x1 + x2 + x3;
#pragma unroll
    for (int off = 1; off < 64; off <<= 1) sum += __shfl_xor(sum, off);
    float mean = sum * (1.0f / 256.0f);
    float d0 = x0 - mean, d1 = x1 - mean, d2 = x2 - mean, d3 = x3 - mean;
    float ss = d0 * d0 + d1 * d1 + d2 * d2 + d3 * d3;
#pragma unroll
    for (int off = 1; off < 64; off <<= 1) ss += __shfl_xor(ss, off);
    float rs = rsqrtf(ss * (1.0f / 256.0f) + 1e-5f);
    u16x4 o;
    o[0] = f2b(d0 * rs * s[4 * l + 0] + b[4 * l + 0]);
    o[1] = f2b(d1 * rs * s[4 * l + 1] + b[4 * l + 1]);
    o[2] = f2b(d2 * rs * s[4 * l + 2] + b[4 * l + 2]);
    o[3] = f2b(d3 * rs * s[4 * l + 3] + b[4 * l + 3]);
    *(u16x4*)&out[r * 256 + 4 * l] = o;
}

// ---------------- CSR build: count, hierarchical scan, fill ----------------
__global__ void ge_count(const int* __restrict__ idx, int* __restrict__ cnt, int n) {
    int i = blockIdx.x * 256 + threadIdx.x;
    if (i < n) atomicAdd(&cnt[idx[i]], 1);
}

__global__ __launch_bounds__(256) void ge_bsum(const int* __restrict__ cnt,
                                               int* __restrict__ bsum, int n) {
    int i = blockIdx.x * 256 + threadIdx.x;
    int v = (i < n) ? cnt[i] : 0;
#pragma unroll
    for (int off = 1; off < 64; off <<= 1) v += __shfl_xor(v, off);
    __shared__ int ws_[4];
    int l = threadIdx.x & 63, w = threadIdx.x >> 6;
    if (l == 0) ws_[w] = v;
    __syncthreads();
    if (threadIdx.x == 0) bsum[blockIdx.x] = ws_[0] + ws_[1] + ws_[2] + ws_[3];
}

__global__ __launch_bounds__(256) void ge_bscan(int* __restrict__ bsum, int nb) {
    __shared__ int lds[256];
    int tid = threadIdx.x;
    int v = (tid < nb) ? bsum[tid] : 0;
    lds[tid] = v;
    __syncthreads();
#pragma unroll
    for (int off = 1; off < 256; off <<= 1) {
        int t = (tid >= off) ? lds[tid - off] : 0;
        __syncthreads();
        lds[tid] += t;
        __syncthreads();
    }
    if (tid < nb) bsum[tid] = lds[tid] - v;  // exclusive
}

__global__ __launch_bounds__(256) void ge_cscan(const int* __restrict__ cnt,
                                                const int* __restrict__ bsum,
                                                int* __restrict__ rowStart,
                                                int* __restrict__ cursor,
                                                float* __restrict__ ldeg, int n) {
    __shared__ int lds[256];
    int tid = threadIdx.x;
    int i = blockIdx.x * 256 + tid;
    int c = (i < n) ? cnt[i] : 0;
    lds[tid] = c;
    __syncthreads();
#pragma unroll
    for (int off = 1; off < 256; off <<= 1) {
        int t = (tid >= off) ? lds[tid - off] : 0;
        __syncthreads();
        lds[tid] += t;
        __syncthreads();
    }
    if (i < n) {
        int ex = bsum[blockIdx.x] + lds[tid] - c;
        rowStart[i] = ex;
        cursor[i] = ex;
        if (ldeg) ldeg[i] = log1pf((float)c);
        if (i == n - 1) rowStart[n] = ex + c;
    }
}

__global__ void ge_fill(const int* __restrict__ idx, int* __restrict__ cursor,
                        int* __restrict__ csr, int n, int modE) {
    int i = blockIdx.x * 256 + threadIdx.x;
    if (i < n) {
        int slot = atomicAdd(&cursor[idx[i]], 1);
        csr[slot] = (modE && i >= modE) ? (i - modE) : i;
    }
}

__global__ void ge_fill_attn(const int* __restrict__ dst, const int* __restrict__ src,
                             const float* __restrict__ eeb, int* __restrict__ cursor,
                             int* __restrict__ csrSrc, float* __restrict__ biasCsr, int n) {
    int i = blockIdx.x * 256 + threadIdx.x;
    if (i < n) {
        int slot = atomicAdd(&cursor[dst[i]], 1);
        csrSrc[slot] = src[i];
        f4v b0 = *(const f4v*)&eeb[(size_t)i * 8];
        f4v b1 = *(const f4v*)&eeb[(size_t)i * 8 + 4];
        *(f4v*)&biasCsr[(size_t)slot * 8] = b0;
        *(f4v*)&biasCsr[(size_t)slot * 8 + 4] = b1;
    }
}

// ---------------- GEMM: 128x128 tile, grouped block order (R10-proven) ----------------
// EPI 1: out bf16 = C + bias + res(f32)          (Wo + residual -> h1 bf16)
// EPI 2: out bf16 = gelu(C + bias)               (W1, ldOut=1024, DIRECT quad-permuted store)
// EPI 3: out f32  = (C+bias+resB)*(c0+ldeg*c1)   (W2 + bf16 residual + deg scale)
// EPI 4: out f32  = C + bias + res(f32)          (We2n + x)
// EPI 5: QKV: q -> outB[E][256]; k,v interleaved 8-wide -> outB2[E][512]
template <int EPI>
__global__ __launch_bounds__(256) void ge_gemm(
    const u16* __restrict__ A, const u16* __restrict__ Bt, int K, int nxt,
    const float* __restrict__ bias, const float* __restrict__ res,
    const u16* __restrict__ resB, const float* __restrict__ ldeg,
    const float* __restrict__ dcoef,
    float* __restrict__ outF, u16* __restrict__ outB, u16* __restrict__ outB2,
    int ldOut) {
    __shared__ __align__(16) char smem[32768];
    const int tid = threadIdx.x;
    const int l = tid & 63, w = tid >> 6;
    // grouped block-order remap (bijective; nxt % 64 == 0 for all our grids)
    const int ny = gridDim.x / nxt;
    const int gsz = 64 * ny;
    const int bid = blockIdx.x;
    const int xt = (bid / gsz) * 64 + (bid % gsz) % 64;
    const int yt = (bid % gsz) / 64;
    const int rowBase = xt * 128, colBase = yt * 128;
    const int ar = tid >> 2, aq = tid & 3;
    const int aqs = aq ^ (ar & 3);  // source-side chunk swizzle (R4/R8-proven)
    const u16* Ag = A + (size_t)(rowBase + ar) * K + aqs * 8;
    const u16* Bg = Bt + (size_t)(colBase + ar) * K + aqs * 8;
    const size_t row64 = (size_t)64 * K;

    f32x4 acc[4][4] = {};
    const int lr = l & 15;
    const int ks2 = (((l >> 4) ^ (l & 3)) << 3);  // read-side swizzled chunk (R4/R8-proven)
    const int wr = (w >> 1) * 64, wc = (w & 1) * 64;
    const int nt = K >> 5;

    auto STAGE = [&](int b, int t) {
        const int kk = t * 32;
        char* dA = smem + b * 8192 + w * 1024;
        char* dB = smem + 16384 + b * 8192 + w * 1024;
        GLDS(Ag + kk, dA);
        GLDS(Ag + kk + row64, dA + 4096);
        GLDS(Bg + kk, dB);
        GLDS(Bg + kk + row64, dB + 4096);
    };

    STAGE(0, 0);
    __syncthreads();
    int cur = 0;
    for (int t = 0; t < nt; ++t) {
        if (t + 1 < nt) STAGE(cur ^ 1, t + 1);
        const u16* bufA = (const u16*)(smem + cur * 8192);
        const u16* bufB = (const u16*)(smem + 16384 + cur * 8192);
        bf16x8 af[4], bfr[4];
#pragma unroll
        for (int mi = 0; mi < 4; mi++) af[mi] = *(const bf16x8*)&bufA[(wr + mi * 16 + lr) * 32 + ks2];
#pragma unroll
        for (int ni = 0; ni < 4; ni++) bfr[ni] = *(const bf16x8*)&bufB[(wc + ni * 16 + lr) * 32 + ks2];
#pragma unroll
        for (int mi = 0; mi < 4; mi++)
#pragma unroll
            for (int ni = 0; ni < 4; ni++)
                acc[mi][ni] = __builtin_amdgcn_mfma_f32_16x16x32_bf16(af[mi], bfr[ni], acc[mi][ni], 0, 0, 0);
        if (t + 1 < nt) {
            __syncthreads();
            cur ^= 1;
        }
    }

    const int r0 = (l >> 4) * 4;
    if constexpr (EPI == 2) {
        // direct store with quad-permuted hidden layout (matches W2T's permuted K).
        // true col = wc+ni*16+lr stored at wc+lr*4+ni; bias/gelu use true col.
        float bv[4];
#pragma unroll
        for (int ni = 0; ni < 4; ni++) bv[ni] = bias[colBase + wc + ni * 16 + lr];
#pragma unroll
        for (int mi = 0; mi < 4; mi++) {
#pragma unroll
            for (int r = 0; r < 4; r++) {
                int grow = rowBase + wr + mi * 16 + r0 + r;
                float v0 = gelu_f(acc[mi][0][r] + bv[0]);
                float v1 = gelu_f(acc[mi][1][r] + bv[1]);
                float v2 = gelu_f(acc[mi][2][r] + bv[2]);
                float v3 = gelu_f(acc[mi][3][r] + bv[3]);
                unsigned lo, hi;
                asm("v_cvt_pk_bf16_f32 %0, %1, %2" : "=v"(lo) : "v"(v0), "v"(v1));
                asm("v_cvt_pk_bf16_f32 %0, %1, %2" : "=v"(hi) : "v"(v2), "v"(v3));
                u32x2 pk; pk[0] = lo; pk[1] = hi;
                *(u32x2*)&outB[(size_t)grow * 1024 + colBase + wc + lr * 4] = pk;
            }
        }
    } else if constexpr (EPI == 5) {
        // bf16 outputs: transpose through LDS with row-group XOR swizzle
        __syncthreads();
        u16* ep = (u16*)smem;  // [128][128]
#pragma unroll
        for (int mi = 0; mi < 4; mi++) {
#pragma unroll
            for (int ni = 0; ni < 4; ni++) {
#pragma unroll
                for (int r = 0; r < 4; r++) {
                    int rl = wr + mi * 16 + r0 + r;
                    int cl = wc + ni * 16 + lr;
                    float c = acc[mi][ni][r] + bias[colBase + cl];
                    ep[rl * 128 + (cl ^ (((rl >> 2) & 3) << 4))] = f2b(c);
                }
            }
        }
        __syncthreads();
#pragma unroll
        for (int j = 0; j < 8; j++) {
            int lin = tid + j * 256;
            int row = lin >> 4, ch = lin & 15;
            int grow = rowBase + row;
            bf16x8 v = *(const bf16x8*)&ep[row * 128 + ((ch * 8) ^ (((row >> 2) & 3) << 4))];
            int gcol0 = colBase + ch * 8;
            u16x4 vlo = *((const u16x4*)&v);
            u16x4 vhi = *(((const u16x4*)&v) + 1);
            if (gcol0 < 256) {
                *(bf16x8*)&outB[(size_t)grow * 256 + gcol0] = v;
            } else if (gcol0 < 512) {
                int d0 = (gcol0 - 256) >> 2;  // even
                *(u16x4*)&outB2[(size_t)grow * 512 + 8 * d0] = vlo;
                *(u16x4*)&outB2[(size_t)grow * 512 + 8 * (d0 + 1)] = vhi;
            } else {
                int d0 = (gcol0 - 512) >> 2;  // even
                *(u16x4*)&outB2[(size_t)grow * 512 + 8 * d0 + 4] = vlo;
                *(u16x4*)&outB2[(size_t)grow * 512 + 8 * (d0 + 1) + 4] = vhi;
            }
        }
    } else {
#pragma unroll
        for (int mi = 0; mi < 4; mi++) {
#pragma unroll
            for (int ni = 0; ni < 4; ni++) {
#pragma unroll
                for (int r = 0; r < 4; r++) {
                    int grow = rowBase + wr + mi * 16 + r0 + r;
                    int gcol = colBase + wc + ni * 16 + lr;
                    float c = acc[mi][ni][r];
                    if constexpr (EPI == 1) {
                        outB[(size_t)grow * ldOut + gcol] =
                            f2b(c + bias[gcol] + res[(size_t)grow * 256 + gcol]);
                    } else if constexpr (EPI == 3) {
                        float t2 = c + bias[gcol] + b2f(resB[(size_t)grow * 256 + gcol]);
                        outF[(size_t)grow * ldOut + gcol] =
                            t2 * (dcoef[2 * gcol] + ldeg[grow] * dcoef[2 * gcol + 1]);
                    } else {
                        outF[(size_t)grow * ldOut + gcol] =
                            c + bias[gcol] + res[(size_t)grow * 256 + gcol];
                    }
                }
            }
        }
    }
}

// ---------------- per-dst-segment attention: single-pass softmax + V agg ----------------
__global__ __launch_bounds__(256) void ge_attn(const u16* __restrict__ qb,
                                               const u16* __restrict__ kvb,
                                               const float* __restrict__ biasCsr,
                                               const int* __restrict__ csrSrc,
                                               const int* __restrict__ rowStart,
                                               u16* __restrict__ agg) {
    int tid = threadIdx.x, l = tid & 63, w = tid >> 6;
    int e = blockIdx.x * 4 + w;
    int g = l >> 3;
    const float scale = 0.17677669529663687f;  // 32^-0.5
    u16x4 qv = *(const u16x4*)&qb[(size_t)e * 256 + 4 * l];
    float q0 = b2f(qv[0]), q1 = b2f(qv[1]), q2 = b2f(qv[2]), q3 = b2f(qv[3]);
    int s0 = rowStart[e], s1 = rowStart[e + 1];

    float sum = 0.0f, a0 = 0.0f, a1 = 0.0f, a2 = 0.0f, a3 = 0.0f;
    if (s0 < s1) {
        int sc = csrSrc[s0];
        bf16x8 kvc = *(const bf16x8*)&kvb[(size_t)sc * 512 + 8 * l];
        float bc = biasCsr[(size_t)s0 * 8 + g];
        for (int i = s0; i < s1; i++) {
            int inx = (i + 1 < s1) ? (i + 1) : i;
            int sn = csrSrc[inx];
            bf16x8 kvn = *(const bf16x8*)&kvb[(size_t)sn * 512 + 8 * l];
            float bn = biasCsr[(size_t)inx * 8 + g];
            float p = q0 * b2f((u16)kvc[0]) + q1 * b2f((u16)kvc[1]) +
                      q2 * b2f((u16)kvc[2]) + q3 * b2f((u16)kvc[3]);
            p += __shfl_xor(p, 1);
            p += __shfl_xor(p, 2);
            p += __shfl_xor(p, 4);
            float ex = __expf(p * scale + bc);  // logits bounded, no max pass needed
            sum += ex;
            a0 += ex * b2f((u16)kvc[4]);
            a1 += ex * b2f((u16)kvc[5]);
            a2 += ex * b2f((u16)kvc[6]);
            a3 += ex * b2f((u16)kvc[7]);
            kvc = kvn;
            bc = bn;
        }
    }
    float inv = 1.0f / (sum + 1e-16f);
    u16x4 o;
    o[0] = f2b(a0 * inv);
    o[1] = f2b(a1 * inv);
    o[2] = f2b(a2 * inv);
    o[3] = f2b(a3 * inv);
    *(u16x4*)&agg[(size_t)e * 256 + 4 * l] = o;
}

// ---------------- node aggregation: sum edge_out rows per node -> bf16 ----------------
__global__ __launch_bounds__(256) void ge_nodeagg(const float* __restrict__ edge_out,
                                                  const int* __restrict__ rowStart,
                                                  const int* __restrict__ csr,
                                                  u16* __restrict__ nmsg) {
    int tid = threadIdx.x, l = tid & 63, w = tid >> 6;
    int n = blockIdx.x * 4 + w;
    int s0 = rowStart[n], s1 = rowStart[n + 1];
    float a0 = 0.0f, a1 = 0.0f, a2 = 0.0f, a3 = 0.0f;
    for (int i = s0; i < s1; i++) {
        int e = csr[i];
        f4v v = *(const f4v*)&edge_out[(size_t)e * 256 + 4 * l];
        a0 += v[0]; a1 += v[1]; a2 += v[2]; a3 += v[3];
    }
    u16x4 o;
    o[0] = f2b(a0); o[1] = f2b(a1); o[2] = f2b(a2); o[3] = f2b(a3);
    *(u16x4*)&nmsg[(size_t)n * 256 + 4 * l] = o;
}

extern "C" void kernel_launch(void* const* d_in, const int* in_sizes, int n_in,
                              void* d_out, int out_size, void* d_ws, size_t ws_size,
                              hipStream_t stream) {
    (void)in_sizes; (void)n_in; (void)out_size; (void)ws_size;
    const float* edge_attr = (const float*)d_in[0];
    const float* x = (const float*)d_in[1];
    const int* src_e = (const int*)d_in[2];
    const int* dst_e = (const int*)d_in[3];
    const int* edge_index = (const int*)d_in[4];
    const float* eeb = (const float*)d_in[5];
    const float* ln1_s = (const float*)d_in[6];
    const float* ln1_b = (const float*)d_in[7];
    const float* Wq = (const float*)d_in[8];
    const float* bq = (const float*)d_in[9];
    const float* Wk = (const float*)d_in[10];
    const float* bk = (const float*)d_in[11];
    const float* Wv = (const float*)d_in[12];
    const float* bv = (const float*)d_in[13];
    const float* Wo = (const float*)d_in[14];
    const float* bo = (const float*)d_in[15];
    const float* ln2_s = (const float*)d_in[16];
    const float* ln2_b = (const float*)d_in[17];
    const float* W1 = (const float*)d_in[18];
    const float* b1 = (const float*)d_in[19];
    const float* W2 = (const float*)d_in[20];
    const float* b2 = (const float*)d_in[21];
    const float* deg_coef = (const float*)d_in[22];
    const float* We2n = (const float*)d_in[23];
    const float* be2n = (const float*)d_in[24];

    char* ws = (char*)d_ws;
    size_t off = 0;
    auto alloc = [&](size_t bytes) { char* p = ws + off; off += (bytes + 255) & ~(size_t)255; return p; };
    u16* qb = (u16*)alloc((size_t)E_ * 256 * 2);
    u16* kvb = (u16*)alloc((size_t)E_ * 512 * 2);
    u16* agg = (u16*)alloc((size_t)E_ * 256 * 2);
    u16* ffh = qb;  // overlays qb+kvb+agg = E*1024*2 exactly
    u16* h1b = (u16*)alloc((size_t)E_ * 256 * 2);  // h1 residual, bf16
    u16* en = (u16*)alloc((size_t)E_ * 256 * 2);
    u16* h1n = en;  // reuse after QKV GEMM
    u16* nmsg = (u16*)alloc((size_t)N_ * 256 * 2);
    u16* WqkvT = (u16*)alloc(768 * 256 * 2);
    float* bqkv = (float*)alloc(768 * 4);
    u16* WoT = (u16*)alloc(256 * 256 * 2);
    u16* W1T = (u16*)alloc(1024 * 256 * 2);
    u16* W2T = (u16*)alloc(256 * 1024 * 2);
    u16* We2nT = (u16*)alloc(256 * 256 * 2);
    int* cntE = (int*)alloc((size_t)E_ * 4);
    int* cntN = (int*)alloc((size_t)N_ * 4);
    int* rowStartE = (int*)alloc((size_t)(E_ + 1) * 4);
    int* cursorE = (int*)alloc((size_t)E_ * 4);
    int* csrSrc = (int*)alloc((size_t)M_ * 4);
    float* biasCsr = (float*)alloc((size_t)M_ * 8 * 4);
    float* ldeg = (float*)alloc((size_t)E_ * 4);
    int* rowStartN = (int*)alloc((size_t)(N_ + 1) * 4);
    int* cursorN = (int*)alloc((size_t)N_ * 4);
    int* csrN = (int*)alloc((size_t)2 * E_ * 4);
    int* bsumE = (int*)alloc(256 * 4);
    int* bsumN = (int*)alloc(64 * 4);

    float* out_edge = (float*)d_out;
    float* out_node = out_edge + (size_t)E_ * 256;

    // CSR + weights prep
    ge_zero<<<(E_ + N_) / 256, 256, 0, stream>>>(cntE, E_ + N_);
    ge_convw<<<3331, 256, 0, stream>>>(Wq, Wk, Wv, bq, bk, bv, Wo, W1, W2, We2n,
                                       WqkvT, bqkv, WoT, W1T, W2T, We2nT);
    ge_ln<0><<<E_ / 4, 256, 0, stream>>>(edge_attr, ln1_s, ln1_b, en);
    ge_count<<<M_ / 256, 256, 0, stream>>>(dst_e, cntE, M_);
    ge_count<<<2 * E_ / 256, 256, 0, stream>>>(edge_index, cntN, 2 * E_);
    ge_bsum<<<E_ / 256, 256, 0, stream>>>(cntE, bsumE, E_);
    ge_bscan<<<1, 256, 0, stream>>>(bsumE, E_ / 256);
    ge_cscan<<<E_ / 256, 256, 0, stream>>>(cntE, bsumE, rowStartE, cursorE, ldeg, E_);
    ge_bsum<<<N_ / 256, 256, 0, stream>>>(cntN, bsumN, N_);
    ge_bscan<<<1, 256, 0, stream>>>(bsumN, N_ / 256);
    ge_cscan<<<N_ / 256, 256, 0, stream>>>(cntN, bsumN, rowStartN, cursorN, nullptr, N_);
    ge_fill_attn<<<M_ / 256, 256, 0, stream>>>(dst_e, src_e, eeb, cursorE, csrSrc, biasCsr, M_);
    ge_fill<<<2 * E_ / 256, 256, 0, stream>>>(edge_index, cursorN, csrN, 2 * E_, E_);

    // QKV projection: en @ WqkvT -> qb (E,256) + kvb (E,512 interleaved)
    ge_gemm<5><<<(E_ / 128) * 6, 256, 0, stream>>>(en, WqkvT, 256, E_ / 128, bqkv,
                                                   nullptr, nullptr, nullptr, nullptr,
                                                   nullptr, qb, kvb, 768);
    // segment attention -> agg bf16 (E,256)
    ge_attn<<<E_ / 4, 256, 0, stream>>>(qb, kvb, biasCsr, csrSrc, rowStartE, agg);
    // Wo + residual -> h1 bf16
    ge_gemm<1><<<(E_ / 128) * 2, 256, 0, stream>>>(agg, WoT, 256, E_ / 128, bo,
                                                   edge_attr, nullptr, nullptr, nullptr,
                                                   nullptr, h1b, nullptr, 256);
    // LN2 -> h1n bf16
    ge_ln<1><<<E_ / 4, 256, 0, stream>>>(h1b, ln2_s, ln2_b, h1n);
    // FFN up + gelu -> ffh bf16 (E,1024, quad-permuted hidden layout)
    ge_gemm<2><<<(E_ / 128) * 8, 256, 0, stream>>>(h1n, W1T, 256, E_ / 128, b1,
                                                   nullptr, nullptr, nullptr, nullptr,
                                                   nullptr, ffh, nullptr, 1024);
    // FFN down + residual + degree scaling -> edge_out f32 (d_out)
    ge_gemm<3><<<(E_ / 128) * 2, 256, 0, stream>>>(ffh, W2T, 1024, E_ / 128, b2,
                                                   nullptr, h1b, ldeg, deg_coef,
                                                   out_edge, nullptr, nullptr, 256);
    // node aggregation -> nmsg bf16 (N,256)
    ge_nodeagg<<<N_ / 4, 256, 0, stream>>>(out_edge, rowStartN, csrN, nmsg);
    // e2n projection + x residual -> node_out f32 (d_out tail)
    ge_gemm<4><<<(N_ / 128) * 2, 256, 0, stream>>>(nmsg, We2nT, 256, N_ / 128, be2n,
                                                   x, nullptr, nullptr, nullptr,
                                                   out_node, nullptr, nullptr, 256);
}